// Round 8
// baseline (264.070 us; speedup 1.0000x reference)
//
#include <hip/hip_runtime.h>
#include <stdint.h>

// ---------------------------------------------------------------------------
// TSA block: out = x + softmax((h Wq)(h Wk)^T / 32) (h Wv),  h = x + pos_enc
// B=4, S=2048, D=1024. fp32 I/O, f16 MFMA internals.
// R14: fine-phase core v2 for QKV + PV (logits stays R12 gemm256, best
//      measured). Two changes vs R13's core, same geometry/epilogues:
//      (1) forced mid-barrier + lgkmcnt(0) + sched_barrier REMOVED — frag
//          reads are IR loads, compiler emits partial lgkmcnt per consuming
//          MFMA (m97), enabling in-wave LDS||MFMA overlap the old structure
//          serialized (768cy reads + 620cy MFMA lockstep = the 28% band).
//          One barrier per phase.
//      (2) 3 LDS regions (48KB) -> 3 blk/CU, 12 waves/CU (+50% TLP).
//      Ledger (lead-2): phase s reads region s%3; stage(s+2)->(s-1)%3 whose
//      reads completed before s-1's end barrier (consuming MFMAs precede
//      it). End-of-phase in-flight {s+1,s+2}=8 loads -> vmcnt(4) ensures
//      s+1 resident; tail vmcnt(0); asm memory clobber pins next phase's
//      reads below the wait. Region offsets = wrap-increment induction vars
//      (R11 lesson: no runtime mod -> no VALU bloat).
// Session facts: 8 schedule variants cluster 24-33% MfmaUtil; [r][32k] LDS
// layout + linear gload_lds staging counter-verified conflict-free;
// max |logit| ~ 8 => exp fits f16.
// ---------------------------------------------------------------------------

#define AS1(p) ((__attribute__((address_space(1))) void*)(p))
#define AS3(p) ((__attribute__((address_space(3))) void*)(p))

typedef _Float16 f16x8 __attribute__((ext_vector_type(8)));
typedef _Float16 f16x4 __attribute__((ext_vector_type(4)));
typedef float f32x4 __attribute__((ext_vector_type(4)));

// ---------------- prep: h = x + pe (f16), Wt = W^T (f16), rowsum = 0 -------
__global__ __launch_bounds__(256) void prep(const float* __restrict__ x,
                                            _Float16* __restrict__ h,
                                            const float* __restrict__ Wq,
                                            const float* __restrict__ Wk,
                                            const float* __restrict__ Wv,
                                            _Float16* __restrict__ Wt,
                                            float* __restrict__ rowsum) {
  const int bx = blockIdx.x;
  const int tid = threadIdx.x;
  if (bx < 8192) {
    const size_t e = ((size_t)bx * 256 + tid) * 4;
    const int d = (int)(e & 1023);
    const int s = (int)((e >> 10) & 2047);
    const float4 xv = *(const float4*)(x + e);
    const int half = d >> 9;
    const int j0 = d & 511;
    const float c = -0.017988946039016f;  // -ln(10000)/512
    f16x4 o;
#pragma unroll
    for (int t = 0; t < 4; t++) {
      const float r = __expf((float)(j0 + t) * c);
      const float a = (float)s * r;
      const float p = half ? __cosf(a) : __sinf(a);
      const float xe = (t == 0) ? xv.x : (t == 1) ? xv.y : (t == 2) ? xv.z : xv.w;
      o[t] = (_Float16)(xe + p);
    }
    *(f16x4*)(h + e) = o;
  } else if (bx < 11264) {
    __shared__ float t[32][33];
    const int w = bx - 8192;
    const int z = w >> 10;
    const int rem = w & 1023;
    const int n0 = (rem & 31) * 32, k0 = (rem >> 5) * 32;
    const float* W = (z == 0) ? Wq : (z == 1) ? Wk : Wv;
    _Float16* o = Wt + (size_t)z * 1048576;
    const int tx = tid & 31, ty = tid >> 5;
#pragma unroll
    for (int i = ty; i < 32; i += 8)
      t[i][tx] = W[(size_t)(k0 + i) * 1024 + (n0 + tx)];
    __syncthreads();
#pragma unroll
    for (int i = ty; i < 32; i += 8)
      o[(size_t)(n0 + i) * 1024 + (k0 + tx)] = (_Float16)t[tx][i];
  } else {
    rowsum[(bx - 11264) * 256 + tid] = 0.f;
  }
}

// ---------------- 128x128 A·B^T GEMM, fine-phase core v2 -------------------
// 3 LDS regions (48KB, 3 blk/CU), lead-2 staging, one barrier/phase,
// compiler-managed lgkmcnt (no forced drain).
// MODE 0 (QKV): grid 1536. q,k: C f16 row-major = A·B + bias(z);
//   z=2 (v): writes vT[b][d][s] directly (f16x4).
// MODE 2 (PV^T norm + res): grid 512.
//   C0[z*sC + n*ldc + m] = (A·B)[m][n]/rowsum[n] + X, float4.
template <int MODE>
__global__ __launch_bounds__(256) void gemm_bt(
    const _Float16* __restrict__ A0, long long sA,
    const _Float16* __restrict__ B0, long long sB,
    void* __restrict__ C0, long long sC,
    const float* __restrict__ aux0, const float* __restrict__ aux1,
    const float* __restrict__ aux2, float* __restrict__ rowsum,
    _Float16* __restrict__ vT,
    long long sX, const int K, const int N, const int ldc) {
  __shared__ __align__(16) _Float16 As[3 * 4096];  // 3 regions x [128r x 32k]
  __shared__ __align__(16) _Float16 Bs[3 * 4096];
  const int tid = threadIdx.x;
  const int bid = blockIdx.x;

  int z, bm0, bn0;
  if (MODE == 0) {
    const int c = bid & 7, t = bid >> 3;
    const int mhi = t & 7, u = t >> 3;
    bm0 = (mhi * 8 + c) * 128;
    bn0 = (u & 7) * 128;
    z = u >> 3;
  } else {
    const int c = bid & 7, t = bid >> 3;
    const int zx = (t & 3) * 8 + c;
    const int y = t >> 2;
    z = zx >> 3; bm0 = (zx & 7) * 128; bn0 = y * 128;
  }
  const _Float16* A = A0 + (size_t)z * sA;
  const _Float16* Bt = B0 + (size_t)z * sB;

  const _Float16* a0 = A + (size_t)(bm0 + (tid >> 2)) * K + (tid & 3) * 8;
  const _Float16* a1 = a0 + (size_t)64 * K;
  const _Float16* b0 = Bt + (size_t)(bn0 + (tid >> 2)) * K + (tid & 3) * 8;
  const _Float16* b1 = b0 + (size_t)64 * K;

  // one stage-unit = 4 gload_lds: 32-k slice kt -> region byte base rbase
  auto stage = [&](int kt, int rbase) {
    const int k = kt * 32;
    __builtin_amdgcn_global_load_lds(AS1(a0 + k), AS3(&As[rbase + tid * 8]), 16, 0, 0);
    __builtin_amdgcn_global_load_lds(AS1(a1 + k), AS3(&As[rbase + tid * 8 + 2048]), 16, 0, 0);
    __builtin_amdgcn_global_load_lds(AS1(b0 + k), AS3(&Bs[rbase + tid * 8]), 16, 0, 0);
    __builtin_amdgcn_global_load_lds(AS1(b1 + k), AS3(&Bs[rbase + tid * 8 + 2048]), 16, 0, 0);
  };

  const int lane = tid & 63, wave = tid >> 6;
  const int wr = wave >> 1, wc = wave & 1;
  const int quad = lane >> 4, l16 = lane & 15;

  f32x4 acc[4][4];
#pragma unroll
  for (int i = 0; i < 4; i++)
#pragma unroll
    for (int j = 0; j < 4; j++) {
      f32x4 zz = {0.f, 0.f, 0.f, 0.f};
      acc[i][j] = zz;
    }

  const int NS = K >> 5;  // 32-k slices (32 or 64 here)

  // prologue: stage slices 0,1; wait unit 0 (allow newest 4 = unit 1)
  stage(0, 0); stage(1, 4096);
  asm volatile("s_waitcnt vmcnt(4)" ::: "memory");
  __builtin_amdgcn_s_barrier();

  int rb = 0;     // region of current slice s
  int sb = 8192;  // region of slice s+2 (= (s-1)%3 slot, free per ledger)
  for (int s = 0; s < NS; ++s) {
    // issue next-next stage first (long-latency; region free per ledger)
    if (s + 2 < NS) stage(s + 2, sb);
    // frag reads: compiler emits partial lgkmcnt before each consuming MFMA
    f16x8 af[4], bf[4];
#pragma unroll
    for (int i = 0; i < 4; i++)
      af[i] = *(const f16x8*)&As[rb + (wr * 64 + i * 16 + l16) * 32 + quad * 8];
#pragma unroll
    for (int j = 0; j < 4; j++)
      bf[j] = *(const f16x8*)&Bs[rb + (wc * 64 + j * 16 + l16) * 32 + quad * 8];
    __builtin_amdgcn_s_setprio(1);
#pragma unroll
    for (int i = 0; i < 4; i++)
#pragma unroll
      for (int j = 0; j < 4; j++)
        acc[i][j] = __builtin_amdgcn_mfma_f32_16x16x32_f16(af[i], bf[j],
                                                           acc[i][j], 0, 0, 0);
    __builtin_amdgcn_s_setprio(0);
    // phase end: ensure slice s+1 resident (in-flight = {s+1, s+2} = 8 loads)
    if (s + 1 < NS) {
      if (s + 2 < NS) asm volatile("s_waitcnt vmcnt(4)" ::: "memory");
      else            asm volatile("s_waitcnt vmcnt(0)" ::: "memory");
      __builtin_amdgcn_s_barrier();
    }
    rb = (rb == 8192) ? 0 : rb + 4096;
    sb = (sb == 8192) ? 0 : sb + 4096;
  }

  // epilogue: C/D layout col = lane&15 (in colb), row = quad*4 + reg
  const int rowb = bm0 + wr * 64 + quad * 4;
  const int colb = bn0 + wc * 64 + l16;
  if (MODE == 0) {
    const float* bias = (z == 0) ? aux0 : (z == 1) ? aux1 : aux2;
    if (z == 2) {
      const int b = rowb >> 11, sl = rowb & 2047;
      _Float16* vb = vT + (size_t)b * 2097152;
#pragma unroll
      for (int i = 0; i < 4; i++)
#pragma unroll
        for (int j = 0; j < 4; j++) {
          const int gn = colb + j * 16;
          const float bb = bias[gn];
          f16x4 o;
#pragma unroll
          for (int r = 0; r < 4; r++) o[r] = (_Float16)(acc[i][j][r] + bb);
          *(f16x4*)&vb[(size_t)gn * 2048 + sl + i * 16] = o;
        }
    } else {
      _Float16* C = (_Float16*)C0 + (size_t)z * sC;
#pragma unroll
      for (int i = 0; i < 4; i++)
#pragma unroll
        for (int j = 0; j < 4; j++) {
          const int gn = colb + j * 16;
          const float bb = bias[gn];
#pragma unroll
          for (int r = 0; r < 4; r++)
            C[(size_t)(rowb + i * 16 + r) * N + gn] = (_Float16)(acc[i][j][r] + bb);
        }
    }
  } else {
    float* C = (float*)C0 + (size_t)z * sC;
    const float* X = aux0 + (size_t)z * sX;
    float inv[4];
#pragma unroll
    for (int j = 0; j < 4; j++)
      inv[j] = 1.0f / rowsum[z * 2048 + colb + j * 16];
#pragma unroll
    for (int i = 0; i < 4; i++)
#pragma unroll
      for (int j = 0; j < 4; j++) {
        const int gn = colb + j * 16;
        const size_t base = (size_t)gn * ldc + rowb + i * 16;
        const float4 xv = *(const float4*)(X + base);
        float4 o;
        o.x = acc[i][j][0] * inv[j] + xv.x;
        o.y = acc[i][j][1] * inv[j] + xv.y;
        o.z = acc[i][j][2] * inv[j] + xv.z;
        o.w = acc[i][j][3] * inv[j] + xv.w;
        *(float4*)(C + base) = o;
      }
  }
}

// ---- gemm256 macros (expand in kernel scope; all indices compile-time) ----
#define RD_A(SET, S_)                                                         \
  {                                                                           \
    _Pragma("unroll") for (int fi = 0; fi < 4; fi++)                          \
      _Pragma("unroll") for (int kk = 0; kk < 2; kk++)                        \
        SET[fi * 2 + kk] = *(const f16x8*)&As[bb][kk][                        \
            (wr * 128 + (S_) * 64 + fi * 16 + l16) * 32 + quad * 8];          \
  }
#define RD_B(SET, S_)                                                         \
  {                                                                           \
    _Pragma("unroll") for (int fj = 0; fj < 2; fj++)                          \
      _Pragma("unroll") for (int kk = 0; kk < 2; kk++)                        \
        SET[fj * 2 + kk] = *(const f16x8*)&Bs[bb][kk][                        \
            (wc * 64 + (S_) * 32 + fj * 16 + l16) * 32 + quad * 8];           \
  }
#define MFMA16(ASET, BSET, MQ, NQ)                                            \
  {                                                                           \
    __builtin_amdgcn_s_setprio(1);                                            \
    _Pragma("unroll") for (int fi = 0; fi < 4; fi++)                          \
      _Pragma("unroll") for (int fj = 0; fj < 2; fj++)                        \
        _Pragma("unroll") for (int kk = 0; kk < 2; kk++)                      \
          acc[(MQ) * 4 + fi][(NQ) * 2 + fj] =                                 \
              __builtin_amdgcn_mfma_f32_16x16x32_f16(                         \
                  ASET[fi * 2 + kk], BSET[fj * 2 + kk],                       \
                  acc[(MQ) * 4 + fi][(NQ) * 2 + fj], 0, 0, 0);                \
    __builtin_amdgcn_s_setprio(0);                                            \
  }
#define PHASE_WAIT()                                                          \
  __builtin_amdgcn_s_barrier();                                               \
  asm volatile("s_waitcnt lgkmcnt(0)" ::: "memory");                          \
  __builtin_amdgcn_sched_barrier(0);

// ---------------- 256x256 exp-logits GEMM, m201 quadrant-phase schedule ----
// (R12 core, verbatim — grid 256 = exactly 1 blk/CU, zero tail)
__global__ __launch_bounds__(512) void gemm256_logits(
    const _Float16* __restrict__ A0, long long sA,
    const _Float16* __restrict__ B0, long long sB,
    void* __restrict__ C0, long long sC,
    float* __restrict__ rowsum, const int K, const int ldc) {
  __shared__ __align__(16) _Float16 As[2][2][8192];  // [buf][kk][256r x 32k]
  __shared__ __align__(16) _Float16 Bs[2][2][8192];
  const int tid = threadIdx.x;
  const int bid = blockIdx.x;

  const int w = (bid & 7) * 32 + (bid >> 3);   // [0,256), XCD chunk 32
  const int z = w >> 6;
  const int r0 = w & 63;
  const int bm0 = (r0 >> 3) * 256, bn0 = (r0 & 7) * 256;

  const _Float16* A = A0 + (size_t)z * sA;
  const _Float16* Bt = B0 + (size_t)z * sB;

  const _Float16* aS = A + (size_t)(bm0 + (tid >> 2)) * K + (tid & 3) * 8;
  const _Float16* bS = Bt + (size_t)(bn0 + (tid >> 2)) * K + (tid & 3) * 8;
  const size_t halfStep = (size_t)128 * K;

  auto stageA = [&](int X, int h) {
    const int b = X & 1;
    const _Float16* s = aS + (size_t)X * 64 + (size_t)h * halfStep;
    _Float16* d = &As[b][0][h * 4096 + tid * 8];
    __builtin_amdgcn_global_load_lds(AS1(s), AS3(d), 16, 0, 0);
    __builtin_amdgcn_global_load_lds(AS1(s + 32), AS3(d + 8192), 16, 0, 0);
  };
  auto stageB = [&](int X, int h) {
    const int b = X & 1;
    const _Float16* s = bS + (size_t)X * 64 + (size_t)h * halfStep;
    _Float16* d = &Bs[b][0][h * 4096 + tid * 8];
    __builtin_amdgcn_global_load_lds(AS1(s), AS3(d), 16, 0, 0);
    __builtin_amdgcn_global_load_lds(AS1(s + 32), AS3(d + 8192), 16, 0, 0);
  };

  const int lane = tid & 63, wave = tid >> 6;
  const int wr = wave >> 2, wc = wave & 3;
  const int quad = lane >> 4, l16 = lane & 15;

  f32x4 acc[8][4];
#pragma unroll
  for (int i = 0; i < 8; i++)
#pragma unroll
    for (int j = 0; j < 4; j++) {
      f32x4 zz = {0.f, 0.f, 0.f, 0.f};
      acc[i][j] = zz;
    }

  const int nt = K >> 6;

  stageA(0, 0); stageA(0, 1); stageB(0, 0); stageB(0, 1);
  stageA(1, 0); stageA(1, 1);
  asm volatile("s_waitcnt vmcnt(4)" ::: "memory");
  __builtin_amdgcn_s_barrier();

  f16x8 a0[8], a1[8], b0f[4], b1f[4];

  for (int T = 0; T < nt; ++T) {
    const int bb = T & 1;
    RD_A(a0, 0);
    RD_B(b0f, 0);
    if (T + 1 < nt) stageB(T + 1, 0);
    PHASE_WAIT();
    MFMA16(a0, b0f, 0, 0);
    __builtin_amdgcn_s_barrier();
    RD_A(a1, 1);
    if (T + 1 < nt) stageB(T + 1, 1);
    PHASE_WAIT();
    MFMA16(a1, b0f, 1, 0);
    __builtin_amdgcn_s_barrier();
    RD_B(b1f, 1);
    if (T + 2 < nt) stageA(T + 2, 0);
    PHASE_WAIT();
    MFMA16(a0, b1f, 0, 1);
    __builtin_amdgcn_s_barrier();
    if (T + 2 < nt) stageA(T + 2, 1);
    PHASE_WAIT();
    MFMA16(a1, b1f, 1, 1);
    if (T + 1 < nt) {
      if (T + 2 < nt) asm volatile("s_waitcnt vmcnt(4)" ::: "memory");
      else            asm volatile("s_waitcnt vmcnt(0)" ::: "memory");
      __builtin_amdgcn_s_barrier();
    }
  }

  const int rowb = bm0 + wr * 128 + quad * 4;
  const int colb = bn0 + wc * 64 + l16;
  _Float16* C = (_Float16*)C0 + (size_t)z * sC;
  float rs[4] = {0.f, 0.f, 0.f, 0.f};
#pragma unroll
  for (int i = 0; i < 8; i++)
#pragma unroll
    for (int j = 0; j < 4; j++) {
      const int gn = colb + j * 16;
      f16x4 o;
      float pj = 0.f;
#pragma unroll
      for (int r = 0; r < 4; r++) {
        const float e = __expf(acc[i][j][r] * 0.03125f);
        o[r] = (_Float16)e;
        pj += e;
      }
      rs[j] += pj;
      *(f16x4*)&C[(size_t)gn * ldc + rowb + i * 16] = o;
    }
#pragma unroll
  for (int j = 0; j < 4; j++) {
    float v = rs[j];
    v += __shfl_xor(v, 16);
    v += __shfl_xor(v, 32);
    if (quad == 0) atomicAdd(&rowsum[z * 2048 + colb + j * 16], v);
  }
}

// ---------------------------------------------------------------------------
extern "C" void kernel_launch(void* const* d_in, const int* in_sizes, int n_in,
                              void* d_out, int out_size, void* d_ws, size_t ws_size,
                              hipStream_t stream) {
  (void)in_sizes; (void)n_in; (void)out_size; (void)ws_size;
  const float* x  = (const float*)d_in[0];
  const float* Wq = (const float*)d_in[1];
  const float* bq = (const float*)d_in[2];
  const float* Wk = (const float*)d_in[3];
  const float* bk = (const float*)d_in[4];
  const float* Wv = (const float*)d_in[5];
  const float* bv = (const float*)d_in[6];
  float* out = (float*)d_out;
  char* ws = (char*)d_ws;

  // workspace layout (bytes):
  //   [0, 16M)        h (f16)          -- dead after QKV
  //   [16M, 22M)      Wt (f16 x3)      -- dead after QKV
  //   [22M, 70M)      qkv: q, k row-major; third slot holds vT[b][d][s]
  //   [70M, 102M)     attn_unnorm = exp(logits) (f16)
  //   [102M, +32K)    rowsum (fp32[8192]), zeroed by prep
  _Float16* h    = (_Float16*)(ws);
  _Float16* Wt   = (_Float16*)(ws + 16777216);
  _Float16* qkv  = (_Float16*)(ws + 23068672);
  _Float16* attn = (_Float16*)(ws + 73400320);
  float* rowsum  = (float*)   (ws + 106954752);

  const long long E = 8388608;  // elements per [8192 x 1024] f16 tensor
  _Float16* vT = qkv + 2 * E;   // [4][1024][2048], written directly by MODE 0

  // prep: [0,8192) make h; [8192,11264) transpose W; [11264,11296) zero rowsum
  prep<<<11296, 256, 0, stream>>>(x, h, Wq, Wk, Wv, Wt, rowsum);

  // QKV: [8192x1024] @ Wt_z -> q,k row-major f16 + bias; v written as vT
  gemm_bt<0><<<1536, 256, 0, stream>>>(
      h, 0LL, Wt, 1048576LL, qkv, E, bq, bk, bv, nullptr, vT,
      0LL, 1024, 1024, 0);

  // exp-logits^T (A=k, Bt=q -> attn[b][q][k] = exp(l/32), rowsum atomics)
  gemm256_logits<<<256, 512, 0, stream>>>(
      qkv + E, 2097152LL, qkv, 2097152LL, attn, 4194304LL,
      rowsum, 1024, 2048);

  // PV^T: A=vT_b, Bt=attn_b -> out[b][s][d] = (P~V)[s][d]/rowsum[s] + x
  gemm_bt<2><<<512, 256, 0, stream>>>(
      vT, 2097152LL, attn, 4194304LL, out, 2097152LL,
      x, nullptr, nullptr, rowsum, nullptr,
      2097152LL, 2048, 2048, 1024);
}